// Round 6
// baseline (4681.630 us; speedup 1.0000x reference)
//
#include <hip/hip_runtime.h>

typedef __attribute__((ext_vector_type(4))) float f32x4;

// All LDS tiles are 64x64 f32, stride 64 words (256B rows), with the T2-style
// XOR swizzle on the 16B chunk index: chunk_slot = chunk ^ (row & 7).
// swzc: byte offset of logical (row, 16B-chunk); involution => same formula
// for read and write.
static __device__ __forceinline__ int swzc(int row, int chunk) {
    return row * 256 + ((chunk ^ (row & 7)) << 4);
}
// word-granular variant for scalar accesses
static __device__ __forceinline__ int swzw(int row, int word) {
    return row * 64 + (((word >> 2) ^ (row & 7)) << 2) + (word & 3);
}

__global__ __launch_bounds__(256, 2)
void head_np32(const float* __restrict__ X, const float* __restrict__ Wq,
               const float* __restrict__ Wk, const float* __restrict__ Wv,
               float* __restrict__ O) {
#pragma clang fp contract(off)
    __shared__ float bufX[4096];  // x staging, later vT[h][s]
    __shared__ float bufQ[4096];  // q[t][h], later attn[t][s] (in-place per row)
    __shared__ float bufK[4096];  // k[s][h]

    const int tid  = threadIdx.x;
    const int wv   = tid >> 6;
    const int lane = tid & 63;
    const size_t b = blockIdx.x;
    const float* xb = X + b * 4096;

    // ---- P0: stage x -> LDS (coalesced global, swizzled LDS) ----
    {
        const int r  = tid >> 2;          // row 0..63
        const int c0 = (tid & 3) * 4;     // 4 chunks of 16B each
        #pragma unroll
        for (int i = 0; i < 4; ++i) {
            f32x4 v = *(const f32x4*)(xb + r * 64 + (c0 + i) * 4);
            *(f32x4*)((char*)bufX + swzc(r, c0 + i)) = v;
        }
    }
    __syncthreads();

    // ---- P1a: x row `lane` -> registers ----
    float xr[64];
    #pragma unroll
    for (int co = 0; co < 16; ++co) {
        f32x4 v = *(const f32x4*)((const char*)bufX + swzc(lane, co));
        xr[4*co+0] = v.x; xr[4*co+1] = v.y; xr[4*co+2] = v.z; xr[4*co+3] = v.w;
    }
    __syncthreads();   // everyone has x in regs before bufX is reused for vT

    // ---- P1b: q,k,v projections. np.matmul == BLAS sgemm: per-element
    //      sequential FMA chain over c=0..63 (one accumulator). lane = t,
    //      this wave handles h in [wv*16, wv*16+16), 4 h at a time with
    //      wave-uniform f32x4 W loads (s_load_dwordx4). Per-output math is
    //      bit-identical to the scalar form: chain over c ascending. ----
    #pragma unroll 1
    for (int h0 = wv * 16; h0 < wv * 16 + 16; h0 += 4) {
        float aq[4] = {0,0,0,0}, ak[4] = {0,0,0,0}, av[4] = {0,0,0,0};
        #pragma unroll
        for (int c = 0; c < 64; ++c) {
            const float xc = xr[c];
            const f32x4 wq4 = *(const f32x4*)(Wq + c * 64 + h0);  // uniform
            const f32x4 wk4 = *(const f32x4*)(Wk + c * 64 + h0);  // uniform
            const f32x4 wv4 = *(const f32x4*)(Wv + c * 64 + h0);  // uniform
            #pragma unroll
            for (int j = 0; j < 4; ++j) {
                aq[j] = fmaf(xc, wq4[j], aq[j]);
                ak[j] = fmaf(xc, wk4[j], ak[j]);
                av[j] = fmaf(xc, wv4[j], av[j]);
            }
        }
        f32x4 q4 = {aq[0], aq[1], aq[2], aq[3]};
        f32x4 k4 = {ak[0], ak[1], ak[2], ak[3]};
        *(f32x4*)((char*)bufQ + swzc(lane, h0 >> 2)) = q4;  // q[t=lane][h0..h0+3]
        *(f32x4*)((char*)bufK + swzc(lane, h0 >> 2)) = k4;  // k[s=lane][h0..h0+3]
        #pragma unroll
        for (int j = 0; j < 4; ++j)
            bufX[swzw(h0 + j, lane)] = av[j];               // vT[h][s=lane]
    }
    __syncthreads();

    // ---- P2: k row `lane` -> regs; scores row-by-row with numpy einsum's
    //      SSE1 semantics: 4 partial sums by (h mod 4), separate mul+add,
    //      ascending h, reduced (L0+L2)+(L1+L3). Then the fp32 quantizer. ----
    float kr[64];
    #pragma unroll
    for (int co = 0; co < 16; ++co) {
        f32x4 v = *(const f32x4*)((const char*)bufK + swzc(lane, co));
        kr[4*co+0] = v.x; kr[4*co+1] = v.y; kr[4*co+2] = v.z; kr[4*co+3] = v.w;
    }
    #pragma unroll 1
    for (int jr = 0; jr < 16; ++jr) {
        const int t = wv + 4 * jr;   // rows interleaved across the 4 waves
        float L0 = 0.f, L1 = 0.f, L2 = 0.f, L3 = 0.f;
        #pragma unroll
        for (int co = 0; co < 16; ++co) {
            f32x4 qv = *(const f32x4*)((const char*)bufQ + swzc(t, co)); // uniform
            L0 += qv.x * kr[4*co+0];   // mul then add (contract off) — NOT fma
            L1 += qv.y * kr[4*co+1];
            L2 += qv.z * kr[4*co+2];
            L3 += qv.w * kr[4*co+3];
        }
        const float score = (L0 + L2) + (L1 + L3);
        const float sc = score * 0.125f;                    // exact (pow2)
        const float f  = (lane <= t) ? fmaxf(sc, 0.0f) : 0.0f;
        float m = f;
        #pragma unroll
        for (int o = 32; o; o >>= 1) m = fmaxf(m, __shfl_xor(m, o));
        float w = floorf((256.0f * f) / (m + 1e-6f));       // all fp32, IEEE
        w = fminf(w, 255.0f);
        w = (w > 127.0f) ? (w - 256.0f) : w;
        // attn[t][s=lane] = w/256 (exact); overwrites q row t — row-exclusive.
        bufQ[swzw(t, lane)] = w * 0.00390625f;
    }
    __syncthreads();

    // ---- P3: out[t][h] = sum_s attn[t][s] * v[s][h]. lane = h, vT row in
    //      regs; accuracy here is tolerance-forgiven (no floor downstream). ----
    float vr[64];
    #pragma unroll
    for (int co = 0; co < 16; ++co) {
        f32x4 v = *(const f32x4*)((const char*)bufX + swzc(lane, co));
        vr[4*co+0] = v.x; vr[4*co+1] = v.y; vr[4*co+2] = v.z; vr[4*co+3] = v.w;
    }
    #pragma unroll 1
    for (int jr = 0; jr < 16; ++jr) {
        const int t = wv + 4 * jr;
        float acc = 0.f;
        #pragma unroll
        for (int co = 0; co < 16; ++co) {
            f32x4 av = *(const f32x4*)((const char*)bufQ + swzc(t, co)); // uniform
            acc = fmaf(av.x, vr[4*co+0], acc);
            acc = fmaf(av.y, vr[4*co+1], acc);
            acc = fmaf(av.z, vr[4*co+2], acc);
            acc = fmaf(av.w, vr[4*co+3], acc);
        }
        O[b * 4096 + t * 64 + lane] = acc;
    }
}

extern "C" void kernel_launch(void* const* d_in, const int* in_sizes, int n_in,
                              void* d_out, int out_size, void* d_ws, size_t ws_size,
                              hipStream_t stream) {
    const float* x  = (const float*)d_in[0];
    const float* Wq = (const float*)d_in[1];
    const float* Wk = (const float*)d_in[2];
    const float* Wv = (const float*)d_in[3];
    float* out = (float*)d_out;
    hipLaunchKernelGGL(head_np32, dim3(8192), dim3(256), 0, stream,
                       x, Wq, Wk, Wv, out);
}

// Round 7
// 449.743 us; speedup vs baseline: 10.4096x; 10.4096x over previous
//
#include <hip/hip_runtime.h>

typedef __attribute__((ext_vector_type(4))) float f32x4;

// -----------------------------------------------------------------------------
// np-fp32-exact fused head. FROZEN numerics (validated R5, absmax 0.03125):
//   q,k:    per-element sequential fmaf chain over c = 0..63 ascending
//   scores: einsum SSE semantics — 4 partial sums by h mod 4, separate
//           mul+add (contract off), ascending h, reduced (L0+L2)+(L1+L3)
//   quantizer: verbatim fp32 (floor(256 f / (m+1e-6)), clip, int8 wrap)
// This round changes only DATAFLOW: no per-lane array > 16 elements
// (R5/R6 spilled xr/kr/vr[64] to scratch -> 8.3 GB HBM traffic, 4.7 ms).
// -----------------------------------------------------------------------------

__global__ __launch_bounds__(256, 3)
void head_np32(const float* __restrict__ X, const float* __restrict__ Wq,
               const float* __restrict__ Wk, const float* __restrict__ Wv,
               float* __restrict__ O) {
#pragma clang fp contract(off)
    // 48 KB LDS -> 3 blocks/CU (3 waves/SIMD)
    __shared__ float xv[4096];  // x rows (16B-chunk XOR-swizzled), later v rows (unswizzled)
    __shared__ float qa[4096];  // q rows (unswizzled), later attn rows (in-place, row-exclusive)
    __shared__ float kb[4096];  // k rows (word-level XOR-swizzled)

    const int tid  = threadIdx.x;
    const int wv   = tid >> 6;         // wave 0..3
    const int lane = tid & 63;
    const size_t b = blockIdx.x;       // one batch per block
    const float* xb = X + b * 4096;

    // ---- P0: stage x. Thread covers row r = tid>>2 (wave w writes exactly
    //      rows [w*16, w*16+16) == its own P1 t-set -> no barrier needed). ----
    {
        const int r = tid >> 2;
        #pragma unroll
        for (int i = 0; i < 4; ++i) {
            const int ch = (tid & 3) * 4 + i;                 // 16B chunk 0..15
            f32x4 v = *(const f32x4*)(xb + r * 64 + ch * 4);
            *(f32x4*)((char*)xv + r * 256 + ((ch ^ (r & 7)) << 4)) = v;
        }
    }

    // ---- P1: q,k,v = x @ W. lane = h; wave owns t in [wv*16, wv*16+16).
    //      acc chain over c ascending (c4 asc, j asc) == np BLAS semantics. ----
    float aq[16], ak[16], av[16];
    #pragma unroll
    for (int i = 0; i < 16; ++i) { aq[i] = 0.f; ak[i] = 0.f; av[i] = 0.f; }

    #pragma unroll 2
    for (int c4 = 0; c4 < 16; ++c4) {
        const int cb = c4 * 4;
        float wqv[4], wkv[4], wvv[4];
        #pragma unroll
        for (int j = 0; j < 4; ++j) {                 // coalesced 256B, L2-hot
            wqv[j] = Wq[(cb + j) * 64 + lane];
            wkv[j] = Wk[(cb + j) * 64 + lane];
            wvv[j] = Wv[(cb + j) * 64 + lane];
        }
        #pragma unroll
        for (int th = 0; th < 2; ++th) {
            f32x4 xr[8];                               // 8 uniform b128 broadcasts
            #pragma unroll
            for (int ii = 0; ii < 8; ++ii) {
                const int t = wv * 16 + th * 8 + ii;   // t&7 == ii (compile-time)
                xr[ii] = *(const f32x4*)((const char*)xv + t * 256 + ((c4 ^ ii) << 4));
            }
            #pragma unroll
            for (int j = 0; j < 4; ++j)
                #pragma unroll
                for (int ii = 0; ii < 8; ++ii) {
                    const int a = th * 8 + ii;
                    aq[a] = fmaf(xr[ii][j], wqv[j], aq[a]);
                    ak[a] = fmaf(xr[ii][j], wkv[j], ak[a]);
                    av[a] = fmaf(xr[ii][j], wvv[j], av[a]);
                }
        }
    }
    // stores: q rows unswizzled; k rows word-swizzled; v overwrites OWN x rows
    #pragma unroll
    for (int i = 0; i < 16; ++i) {
        const int t = wv * 16 + i;
        qa[t * 64 + lane] = aq[i];
        kb[t * 64 + ((((lane >> 2) ^ (i & 7)) << 2) | (lane & 3))] = ak[i];
        xv[t * 64 + lane] = av[i];
    }
    __syncthreads();   // q,k cross-wave in P2

    // ---- P2: scores + quantizer. lane = s; wave owns t = wv + 4*jr
    //      (interleaved for balance). k row of lane held as 16 static f32x4. ----
    f32x4 kr[16];
    #pragma unroll
    for (int co = 0; co < 16; ++co)
        kr[co] = *(const f32x4*)((const char*)kb + lane * 256 + ((co ^ (lane & 7)) << 4));

    #pragma unroll 1
    for (int jr = 0; jr < 16; ++jr) {
        const int t = wv + 4 * jr;
        float L0 = 0.f, L1 = 0.f, L2 = 0.f, L3 = 0.f;
        #pragma unroll
        for (int co = 0; co < 16; ++co) {
            f32x4 qv = *(const f32x4*)((const char*)qa + t * 256 + (co << 4)); // uniform
            L0 += qv.x * kr[co].x;     // mul then add — NOT fma (contract off)
            L1 += qv.y * kr[co].y;
            L2 += qv.z * kr[co].z;
            L3 += qv.w * kr[co].w;
        }
        const float score = (L0 + L2) + (L1 + L3);
        const float sc = score * 0.125f;                  // exact (pow2)
        const float f  = (lane <= t) ? fmaxf(sc, 0.0f) : 0.0f;
        float m = f;
        #pragma unroll
        for (int o = 32; o; o >>= 1) m = fmaxf(m, __shfl_xor(m, o));
        float w = floorf((256.0f * f) / (m + 1e-6f));     // all fp32, IEEE
        w = fminf(w, 255.0f);
        w = (w > 127.0f) ? (w - 256.0f) : w;
        qa[t * 64 + lane] = w * 0.00390625f;   // attn row t (exact); row-exclusive
    }
    __syncthreads();   // attn rows + v rows cross-wave in P3

    // ---- P3: out[t][h] = sum_{s<=t} attn[t][s] * v[s][h]. lane = h;
    //      causal pruning: group s4 contributes to t = wv+4i only if i >= s4. ----
    float po[16];
    #pragma unroll
    for (int i = 0; i < 16; ++i) po[i] = 0.f;

    #pragma unroll
    for (int s4 = 0; s4 < 16; ++s4) {
        float vrow[4];
        #pragma unroll
        for (int j = 0; j < 4; ++j)
            vrow[j] = xv[(s4 * 4 + j) * 64 + lane];       // conflict-free row reads
        #pragma unroll
        for (int i = 0; i < 16; ++i) {
            if (i < s4) continue;                          // attn == 0 there (causal)
            const int t = wv + 4 * i;
            f32x4 a4 = *(const f32x4*)((const char*)qa + t * 256 + (s4 << 4)); // uniform
            po[i] = fmaf(a4.x, vrow[0], po[i]);
            po[i] = fmaf(a4.y, vrow[1], po[i]);
            po[i] = fmaf(a4.z, vrow[2], po[i]);
            po[i] = fmaf(a4.w, vrow[3], po[i]);
        }
    }
    #pragma unroll
    for (int i = 0; i < 16; ++i)
        O[b * 4096 + (wv + 4 * i) * 64 + lane] = po[i];    // coalesced 256B stores
}

extern "C" void kernel_launch(void* const* d_in, const int* in_sizes, int n_in,
                              void* d_out, int out_size, void* d_ws, size_t ws_size,
                              hipStream_t stream) {
    const float* x  = (const float*)d_in[0];
    const float* Wq = (const float*)d_in[1];
    const float* Wk = (const float*)d_in[2];
    const float* Wv = (const float*)d_in[3];
    float* out = (float*)d_out;
    hipLaunchKernelGGL(head_np32, dim3(8192), dim3(256), 0, stream,
                       x, Wq, Wk, Wv, out);
}